// Round 12
// baseline (391.561 us; speedup 1.0000x reference)
//
#include <hip/hip_runtime.h>
#include <stdint.h>

// sample_and_group: B=8 N=8192 C=64 S=2048 K=32 OUT=128
// out = (out[8,2048,128], sampled_coor[8,2048,3]) concatenated in d_out (float32).
//
// R11 fix: kknn was occupancy/latency-bound (LDS 35.8KB -> 4 blocks/CU, occ 42%,
// VALUBusy 49%). Rewritten at 512 thr/block with dist[16] in REGISTERS (no sdist
// LDS; ~4KB total -> occupancy cap 100%), 3-level bitonic merge tree for T.
// Selected knn sets provably identical (exact 32 smallest u64 keys) -> absmax
// unchanged. Everything else byte-identical to R11.
//
// Workspace layout (bytes):
//   [0,2MB)        knn indices  int32[16384*32]
//   [2MB,10MB)     m = max_k y2 f32[16384*128]
//   [10MB,11MB)    coor4 float4[8*8192]   (ALIASES part1; kknn-only lifetime)
//   [10MB,12MB)    partials1    f32[2048*256]
//   [12MB,14MB)    partials2    f32[2048*256]
//   [14MB,+32KB)   w1b  bf16 [o][k=0..127]
//   [..,+32KB)     w2b  bf16 [o][k=0..127]
//   [..,+1KB)      stats1 (scale[128], shift[128])
//   [..,+1KB)      stats2
//   [..,+128KB)    dbuf f64[64*256] (reduce stage-1 output)

#define N_    8192
#define GPB_  8       // groups per block in phase kernels

typedef __attribute__((ext_vector_type(8))) short bf8;
typedef __attribute__((ext_vector_type(16))) float f32x16;

__device__ __forceinline__ unsigned int bf1u(float f) {   // RNE fp32->bf16 bits
  unsigned int u = __float_as_uint(f);
  return (u + 0x7fffu + ((u >> 16) & 1u)) >> 16;
}
__device__ __forceinline__ unsigned int bfpair(float lo, float hi) {
  return bf1u(lo) | (bf1u(hi) << 16);
}

// ---------------- prep: weight layouts + coor4 pack + sampled_coor ------------
__global__ __launch_bounds__(256) void kprep(const float* __restrict__ w1,
                                             const float* __restrict__ w2,
                                             const float* __restrict__ coor,
                                             const int* __restrict__ indx,
                                             unsigned short* __restrict__ w1b,
                                             unsigned short* __restrict__ w2b,
                                             float* __restrict__ outc,
                                             float4* __restrict__ coor4) {
  int e = blockIdx.x * 256 + threadIdx.x;   // grid is exactly 576*256 = 147456
  if (e < 16384) {                           // w1b[o][k] = bf16(w1[o][k])
    w1b[e] = (unsigned short)bf1u(w1[e]);
  } else if (e < 32768) {                    // w2b[o][k] = bf16(w2[o][k])
    int e2 = e - 16384;
    w2b[e2] = (unsigned short)bf1u(w2[e2]);
  } else if (e < 81920) {
    int e2 = e - 32768;                      // 0..49151 sampled_coor
    int bs = e2 / 3, c = e2 - bs * 3;
    int b = bs >> 11, s = bs & 2047;
    outc[e2] = coor[(b * N_ + indx[s]) * 3 + c];
  } else {
    int p = e - 81920;                       // 0..65535 coor4 pack
    const float* src = coor + (size_t)p * 3;
    coor4[p] = make_float4(src[0], src[1], src[2], 0.f);
  }
}

// ---------------- KNN: threshold-select, one query per 512-thread block -------
// Output = SET of 32 smallest keys (dist_bits<<32 | idx); order arbitrary
// (downstream max/mean/var are permutation-invariant over K).
__global__ __launch_bounds__(512, 4) void kknn(const float4* __restrict__ coor4,
                                               const int* __restrict__ indx,
                                               int* __restrict__ knn) {
  __shared__ float smin[256];                 // 8 waves x 32 smallest thread-mins
  __shared__ float smrg1[128];                // level-1 merge outputs
  __shared__ float smrg2[64];                 // level-2 merge outputs
  __shared__ float sT;
  __shared__ unsigned long long cands[128];
  __shared__ unsigned long long ssort[128];
  __shared__ int ccnt;

  const int gid = blockIdx.x;
  const int b = gid >> 11, s = gid & 2047;
  const int tid = threadIdx.x;
  const int w = tid >> 6, lane = tid & 63;
  const float4* cb = coor4 + ((size_t)b << 13);
  const float4 q = cb[indx[s]];

  // pass 1: 16 exact distances in registers; track thread-min
  float dist[16];
  float dmin = 3.4e38f;
#pragma unroll
  for (int it = 0; it < 16; ++it) {
    const float4 c = cb[tid + (it << 9)];
    const float dx = __fsub_rn(c.x, q.x);
    const float dy = __fsub_rn(c.y, q.y);
    const float dz = __fsub_rn(c.z, q.z);
    const float d =
        __fadd_rn(__fadd_rn(__fmul_rn(dx, dx), __fmul_rn(dy, dy)), __fmul_rn(dz, dz));
    dist[it] = d;
    dmin = fminf(dmin, d);
  }
  if (tid == 0) ccnt = 0;
  if (tid < 128) cands[tid] = ~0ULL;

  // pass 2: T = exact 32nd smallest of the 512 thread-mins.
  // (T >= d32: at most 31 points lie strictly below d32, so at most 31
  //  thread-mins do; the 32nd-smallest min is >= d32. Dropping lanes 32-63 of
  //  each wave-sorted list is safe: each dropped value has >=32 values <= it.)
  float v = dmin;                             // per-wave bitonic sort (ascending)
#pragma unroll
  for (int k = 2; k <= 64; k <<= 1) {
#pragma unroll
    for (int j = k >> 1; j >= 1; j >>= 1) {
      const float o = __shfl_xor(v, j, 64);
      const bool dirAsc = ((lane & k) == 0);
      const bool lower = ((lane & j) == 0);
      const float lo = fminf(v, o), hi = fmaxf(v, o);
      v = (dirAsc == lower) ? lo : hi;
    }
  }
  if (lane < 32) smin[w * 32 + lane] = v;
  __syncthreads();
  if (w < 4) {                                // level 1: merge (2w, 2w+1)
    float a = (lane < 32) ? smin[w * 64 + lane] : smin[w * 64 + 32 + (63 - lane)];
#pragma unroll
    for (int j = 32; j >= 1; j >>= 1) {
      const float o = __shfl_xor(a, j, 64);
      const float lo = fminf(a, o), hi = fmaxf(a, o);
      a = ((lane & j) == 0) ? lo : hi;
    }
    if (lane < 32) smrg1[w * 32 + lane] = a;
  }
  __syncthreads();
  if (w < 2) {                                // level 2
    float a = (lane < 32) ? smrg1[w * 64 + lane] : smrg1[w * 64 + 32 + (63 - lane)];
#pragma unroll
    for (int j = 32; j >= 1; j >>= 1) {
      const float o = __shfl_xor(a, j, 64);
      const float lo = fminf(a, o), hi = fmaxf(a, o);
      a = ((lane & j) == 0) ? lo : hi;
    }
    if (lane < 32) smrg2[w * 32 + lane] = a;
  }
  __syncthreads();
  if (w == 0) {                               // level 3 -> 32nd smallest value
    float a = (lane < 32) ? smrg2[lane] : smrg2[32 + (63 - lane)];
#pragma unroll
    for (int j = 32; j >= 1; j >>= 1) {
      const float o = __shfl_xor(a, j, 64);
      const float lo = fminf(a, o), hi = fmaxf(a, o);
      a = ((lane & j) == 0) ? lo : hi;
    }
    if (lane == 31) sT = a;
  }
  __syncthreads();
  const float T = sT;

  // pass 3: compact candidates (dist <= T) from registers; E~34, cap 128
#pragma unroll
  for (int it = 0; it < 16; ++it) {
    if (dist[it] <= T) {
      const int pos = atomicAdd(&ccnt, 1);
      if (pos < 128)
        cands[pos] = ((unsigned long long)__float_as_uint(dist[it]) << 32) |
                     (unsigned int)(tid + (it << 9));
    }
  }
  __syncthreads();

  // pass 4: exact top-32 of <=128 candidates by u64 key
  if (w < 2) {                                // two parallel bitonic sort-64s
    unsigned long long kv = cands[w * 64 + lane];
#pragma unroll
    for (int k = 2; k <= 64; k <<= 1) {
#pragma unroll
      for (int j = k >> 1; j >= 1; j >>= 1) {
        const unsigned long long o = __shfl_xor(kv, j, 64);
        const bool dirAsc = ((lane & k) == 0);
        const bool lower = ((lane & j) == 0);
        const unsigned long long lo = o < kv ? o : kv;
        const unsigned long long hi = o < kv ? kv : o;
        kv = (dirAsc == lower) ? lo : hi;
      }
    }
    ssort[w * 64 + lane] = kv;
  }
  __syncthreads();
  if (w == 0) {                               // reverse-merge; lo-half holds 64 smallest
    const unsigned long long a = ssort[lane];
    const unsigned long long b2 = ssort[64 + 63 - lane];
    unsigned long long m = a < b2 ? a : b2;   // bitonic 64-seq
#pragma unroll
    for (int j = 32; j >= 1; j >>= 1) {
      const unsigned long long o = __shfl_xor(m, j, 64);
      const unsigned long long lo = o < m ? o : m;
      const unsigned long long hi = o < m ? m : o;
      m = ((lane & j) == 0) ? lo : hi;
    }
    if (lane < 32) knn[gid * 32 + lane] = (int)(unsigned int)m;
  }
}

// ---------------- phase kernels: MFMA fused GEMMs ----------------------------
// Wave w owns cols 32w..32w+31. Per lane: m = lane&31 (A row / D col), q2 = lane>>5.
// A layout: A[m=lane&31][k=q2*8+j]; B layout: B^T[n=lane&31][k=q2*8+j];
// C/D layout: col=lane&31, row=(reg&3)+8*(reg>>2)+4*q2  [m74/m101-verified].
// Layer-1 is K=128: A = [sx bf16 (k<64) | d bf16 (k>=64)], B = full w1.
// XCD map: batch = blockIdx&7 (one 2MB x-slice per XCD L2); depth-1 prefetch
// of indx/sx-row/knn-row for group g+1 overlaps group g's staging+MFMA.
template <int PHASE>
__global__ __launch_bounds__(256, 4) void kphase(
    const float* __restrict__ x, const int* __restrict__ indx,
    const int* __restrict__ knn, const float* __restrict__ b1,
    const unsigned short* __restrict__ w1b, const unsigned short* __restrict__ w2b,
    const float* __restrict__ b2, const float* __restrict__ st1,
    float* __restrict__ part, float* __restrict__ mout) {
  __shared__ __align__(16) float sx[64];
  __shared__ __align__(16) unsigned short sxb[72];   // bf16 sx (64 + pad)
  __shared__ __align__(16) unsigned short dls[32 * 68 + 8];
  __shared__ __align__(16) unsigned short h1[PHASE == 2 ? 32 * 136 : 8];

  const int tid = threadIdx.x;
  const int w = tid >> 6;
  const int lane = tid & 63;
  const int m = lane & 31, q2 = lane >> 5;
  const int col = (w << 5) + m;              // output channel of this lane
  const int r8 = tid >> 3, c8 = (tid & 7) * 8;  // staging map: row, col-base

  const int bb = blockIdx.x & 7;             // batch == target XCD
  const int jj = blockIdx.x >> 3;            // 0..255 chunk within batch
  const float* xb = x + (size_t)bb * (N_ * 64);
  const int gidbase = (bb << 11) + jj * GPB_;

  // group-invariant operands in registers
  bf8 bf1[8];
#pragma unroll
  for (int t = 0; t < 8; ++t)
    bf1[t] = *(const bf8*)&w1b[col * 128 + t * 16 + q2 * 8];
  bf8 bf2[8];
  float s1 = 0.f, t1 = 0.f, b2v = 0.f;
  if constexpr (PHASE == 2) {
#pragma unroll
    for (int t = 0; t < 8; ++t)
      bf2[t] = *(const bf8*)&w2b[col * 128 + t * 16 + q2 * 8];
    s1 = st1[col];
    t1 = st1[128 + col];
    b2v = b2[col];
  }
  (void)w2b; (void)b2; (void)st1; (void)mout;
  const float b1c = b1[col];

  float sum = 0.f, ssq = 0.f;

  // depth-1 prefetch for g = 0
  int idxp = indx[jj * GPB_];
  float sxv = (tid < 64) ? xb[(size_t)idxp * 64 + tid] : 0.f;
  int nbr = knn[(size_t)gidbase * 32 + r8];

#pragma unroll 1
  for (int g = 0; g < GPB_; ++g) {
    const int gid = gidbase + g;
    if (tid < 64) sx[tid] = sxv;
    __syncthreads();                         // A: sx visible; prior dls reads done

    // stage d = x[nbr] - sx as bf16 into dls (coalesced: 8 lanes per row)
    {
      const float* xrow = xb + (size_t)nbr * 64 + c8;
      const float4 xa = *(const float4*)(xrow);
      const float4 xc = *(const float4*)(xrow + 4);
      const float4 sa = *(const float4*)(sx + c8);
      const float4 sc = *(const float4*)(sx + c8 + 4);
      uint2 lo, hi;
      lo.x = bfpair(xa.x - sa.x, xa.y - sa.y);
      lo.y = bfpair(xa.z - sa.z, xa.w - sa.w);
      hi.x = bfpair(xc.x - sc.x, xc.y - sc.y);
      hi.y = bfpair(xc.z - sc.z, xc.w - sc.w);
      *(uint2*)&dls[r8 * 68 + c8] = lo;      // byte addr 136*r8+16k: 8B-aligned
      *(uint2*)&dls[r8 * 68 + c8 + 4] = hi;
    }
    if (tid < 16) {                          // pack sx -> bf16 (post-A)
      const float4 sv = *(const float4*)(sx + tid * 4);
      uint2 p;
      p.x = bfpair(sv.x, sv.y);
      p.y = bfpair(sv.z, sv.w);
      *(uint2*)&sxb[tid * 4] = p;
    }

    // prefetch g+1 chain (overlaps this group's MFMA; independent of LDS)
    if (g + 1 < GPB_) {
      const int s1n = jj * GPB_ + g + 1;
      const int idx1 = indx[s1n];
      sxv = (tid < 64) ? xb[(size_t)idx1 * 64 + tid] : 0.f;
      nbr = knn[(size_t)(gid + 1) * 32 + r8];
    }
    __syncthreads();                         // B: dls + sxb ready

    // A-frags: t<4 from sxb (k<64), t>=4 from dls (k>=64)
    bf8 af[8];
#pragma unroll
    for (int t = 0; t < 4; ++t) {
      union { bf8 v; uint2 u[2]; } fa;
      fa.u[0] = *(const uint2*)&sxb[t * 16 + q2 * 8];
      fa.u[1] = *(const uint2*)&sxb[t * 16 + q2 * 8 + 4];
      af[t] = fa.v;
    }
#pragma unroll
    for (int t = 0; t < 4; ++t) {
      union { bf8 v; uint2 u[2]; } fa;
      fa.u[0] = *(const uint2*)&dls[m * 68 + t * 16 + q2 * 8];
      fa.u[1] = *(const uint2*)&dls[m * 68 + t * 16 + q2 * 8 + 4];
      af[4 + t] = fa.v;
    }

    f32x16 acc;
#pragma unroll
    for (int r = 0; r < 16; ++r) acc[r] = b1c;
#pragma unroll
    for (int t = 0; t < 8; ++t)
      acc = __builtin_amdgcn_mfma_f32_32x32x16_bf16(af[t], bf1[t], acc, 0, 0, 0);

    if constexpr (PHASE == 1) {
#pragma unroll
      for (int r = 0; r < 16; ++r) {
        const float v = acc[r];
        sum += v;
        ssq = fmaf(v, v, ssq);
      }
    } else {
      // bn1 + relu -> h1 bf16 in LDS (C-layout scatter, row stride 136)
#pragma unroll
      for (int r = 0; r < 16; ++r) {
        const float hv = fmaxf(0.f, fmaf(acc[r], s1, t1));
        const int row = (r & 3) + ((r >> 2) << 3) + (q2 << 2);
        h1[row * 136 + col] = (unsigned short)bf1u(hv);
      }
      __syncthreads();                       // C: h1 ready

      f32x16 acc2;
#pragma unroll
      for (int r = 0; r < 16; ++r) acc2[r] = b2v;
#pragma unroll
      for (int t = 0; t < 8; ++t) {
        const bf8 a2 = *(const bf8*)&h1[m * 136 + t * 16 + q2 * 8];
        acc2 = __builtin_amdgcn_mfma_f32_32x32x16_bf16(a2, bf2[t], acc2, 0, 0, 0);
      }

      float mx = -1e30f;
#pragma unroll
      for (int r = 0; r < 16; ++r) {
        const float v = acc2[r];
        sum += v;
        ssq = fmaf(v, v, ssq);
        mx = fmaxf(mx, v);
      }
      mx = fmaxf(mx, __shfl_xor(mx, 32, 64));
      if (lane < 32) mout[(size_t)gid * 128 + col] = mx;
    }
  }

  // channel partials: each channel owned by exactly one wave
  sum += __shfl_xor(sum, 32, 64);
  ssq += __shfl_xor(ssq, 32, 64);
  if (lane < 32) {
    part[blockIdx.x * 256 + col] = sum;
    part[blockIdx.x * 256 + 128 + col] = ssq;
  }
}

// ---------------- stats reduce stage 1: 64 blocks, f64 partial sums ----------
__global__ __launch_bounds__(256) void kred1(const float* __restrict__ part,
                                             double* __restrict__ dbuf) {
  const int blk = blockIdx.x;                // 0..63: rows 32*blk..32*blk+31
  const int c = threadIdx.x;                 // 0..255 (128 sums | 128 ssqs)
  const float* p = part + (size_t)blk * 32 * 256 + c;
  double acc = 0.0;
#pragma unroll 8
  for (int r = 0; r < 32; ++r) acc += (double)p[r * 256];
  dbuf[blk * 256 + c] = acc;
}

// ---------------- stats reduce stage 2: finalize scale/shift -----------------
__global__ __launch_bounds__(256) void kred2(const double* __restrict__ dbuf,
                                             const float* __restrict__ gam,
                                             const float* __restrict__ bet,
                                             float* __restrict__ st) {
  __shared__ double sS[256];
  const int c = threadIdx.x;
  double acc = 0.0;
#pragma unroll 8
  for (int i = 0; i < 64; ++i) acc += dbuf[i * 256 + c];
  sS[c] = acc;
  __syncthreads();
  if (c < 128) {
    const double Sv = sS[c], SSv = sS[128 + c];
    const double cnt = 524288.0;             // B*S*K
    const double mean = Sv / cnt;
    const double var = SSv / cnt - mean * mean;
    const double scale = (double)gam[c] / sqrt(var + 1e-5);
    st[c] = (float)scale;
    st[128 + c] = (float)((double)bet[c] - mean * scale);
  }
}

// ---------------- final: out = relu(scale2 * max_k(y2) + shift2) -------------
__global__ __launch_bounds__(256) void kout(const float* __restrict__ m,
                                            const float* __restrict__ st2,
                                            float* __restrict__ out) {
  const int e4 = blockIdx.x * 256 + threadIdx.x;  // 524288 float4s
  const int o0 = (e4 & 31) * 4;
  const float4 v = ((const float4*)m)[e4];
  const float4 sc = *(const float4*)&st2[o0];
  const float4 sh = *(const float4*)&st2[128 + o0];
  float4 r;
  r.x = fmaxf(0.f, fmaf(v.x, sc.x, sh.x));
  r.y = fmaxf(0.f, fmaf(v.y, sc.y, sh.y));
  r.z = fmaxf(0.f, fmaf(v.z, sc.z, sh.z));
  r.w = fmaxf(0.f, fmaf(v.w, sc.w, sh.w));
  ((float4*)out)[e4] = r;
}

extern "C" void kernel_launch(void* const* d_in, const int* in_sizes, int n_in,
                              void* d_out, int out_size, void* d_ws, size_t ws_size,
                              hipStream_t stream) {
  (void)in_sizes; (void)n_in; (void)out_size; (void)ws_size;
  const float* x    = (const float*)d_in[0];
  const float* coor = (const float*)d_in[1];
  const int*   indx = (const int*)d_in[2];
  const float* w1   = (const float*)d_in[3];
  const float* b1   = (const float*)d_in[4];
  const float* g1   = (const float*)d_in[5];
  const float* be1  = (const float*)d_in[6];
  const float* w2   = (const float*)d_in[7];
  const float* b2   = (const float*)d_in[8];
  const float* g2   = (const float*)d_in[9];
  const float* be2  = (const float*)d_in[10];
  float* out = (float*)d_out;

  char* ws = (char*)d_ws;
  int*            knn   = (int*)(ws + 0);
  float*          mbuf  = (float*)(ws + 2097152);
  float*          part1 = (float*)(ws + 10485760);
  float4*         coor4 = (float4*)(ws + 10485760); // aliases part1 (disjoint lifetime)
  float*          part2 = (float*)(ws + 12582912);
  unsigned short* w1b   = (unsigned short*)(ws + 14680064);
  unsigned short* w2b   = (unsigned short*)(ws + 14712832);
  float*          st1   = (float*)(ws + 14745600);
  float*          st2   = (float*)(ws + 14746624);
  double*         dbuf  = (double*)(ws + 14747648);

  float* outc = out + 2097152;   // sampled_coor region of d_out

  kprep<<<576, 256, 0, stream>>>(w1, w2, coor, indx, w1b, w2b, outc, coor4);
  kknn<<<16384, 512, 0, stream>>>(coor4, indx, knn);
  kphase<1><<<2048, 256, 0, stream>>>(x, indx, knn, b1, w1b, w2b, b2, nullptr,
                                      part1, nullptr);
  kred1<<<64, 256, 0, stream>>>(part1, dbuf);
  kred2<<<1, 256, 0, stream>>>(dbuf, g1, be1, st1);
  kphase<2><<<2048, 256, 0, stream>>>(x, indx, knn, b1, w1b, w2b, b2, st1,
                                      part2, mbuf);
  kred1<<<64, 256, 0, stream>>>(part2, dbuf);
  kred2<<<1, 256, 0, stream>>>(dbuf, g2, be2, st2);
  kout<<<2048, 256, 0, stream>>>(mbuf, st2, out);
}

// Round 14
// 289.199 us; speedup vs baseline: 1.3540x; 1.3540x over previous
//
#include <hip/hip_runtime.h>
#include <stdint.h>

// sample_and_group: B=8 N=8192 C=64 S=2048 K=32 OUT=128
// out = (out[8,2048,128], sampled_coor[8,2048,3]) concatenated in d_out (float32).
//
// R13 post-mortem: the pass-3 distance-RECOMPUTE kknn crashed twice (R6, R13)
// while LDS-read (R7/R11) and register-read (R12) pass-3 variants always pass.
// Recompute is banned. This round: hybrid of the two PASSING structures —
// dist[0..15] in registers (R12: spill-free, 44 VGPR) + dist[16..31] in LDS
// (16KB). Block LDS ~18.6KB -> 8 blocks/CU (was 4); __launch_bounds__(256,8).
// Candidate set read from stored bit-exact distances -> knn identical.
// Everything outside kknn byte-identical to R11 (last good, 334.5us).
//
// Workspace layout (bytes):
//   [0,2MB)        knn indices  int32[16384*32]
//   [2MB,10MB)     m = max_k y2 f32[16384*128]
//   [10MB,11MB)    coor4 float4[8*8192]   (ALIASES part1; kknn-only lifetime)
//   [10MB,12MB)    partials1    f32[2048*256]
//   [12MB,14MB)    partials2    f32[2048*256]
//   [14MB,+32KB)   w1b  bf16 [o][k=0..127]
//   [..,+32KB)     w2b  bf16 [o][k=0..127]
//   [..,+1KB)      stats1 (scale[128], shift[128])
//   [..,+1KB)      stats2
//   [..,+128KB)    dbuf f64[64*256] (reduce stage-1 output)

#define N_    8192
#define GPB_  8       // groups per block in phase kernels

typedef __attribute__((ext_vector_type(8))) short bf8;
typedef __attribute__((ext_vector_type(16))) float f32x16;

__device__ __forceinline__ unsigned int bf1u(float f) {   // RNE fp32->bf16 bits
  unsigned int u = __float_as_uint(f);
  return (u + 0x7fffu + ((u >> 16) & 1u)) >> 16;
}
__device__ __forceinline__ unsigned int bfpair(float lo, float hi) {
  return bf1u(lo) | (bf1u(hi) << 16);
}

// ---------------- prep: weight layouts + coor4 pack + sampled_coor ------------
__global__ __launch_bounds__(256) void kprep(const float* __restrict__ w1,
                                             const float* __restrict__ w2,
                                             const float* __restrict__ coor,
                                             const int* __restrict__ indx,
                                             unsigned short* __restrict__ w1b,
                                             unsigned short* __restrict__ w2b,
                                             float* __restrict__ outc,
                                             float4* __restrict__ coor4) {
  int e = blockIdx.x * 256 + threadIdx.x;   // grid is exactly 576*256 = 147456
  if (e < 16384) {                           // w1b[o][k] = bf16(w1[o][k])
    w1b[e] = (unsigned short)bf1u(w1[e]);
  } else if (e < 32768) {                    // w2b[o][k] = bf16(w2[o][k])
    int e2 = e - 16384;
    w2b[e2] = (unsigned short)bf1u(w2[e2]);
  } else if (e < 81920) {
    int e2 = e - 32768;                      // 0..49151 sampled_coor
    int bs = e2 / 3, c = e2 - bs * 3;
    int b = bs >> 11, s = bs & 2047;
    outc[e2] = coor[(b * N_ + indx[s]) * 3 + c];
  } else {
    int p = e - 81920;                       // 0..65535 coor4 pack
    const float* src = coor + (size_t)p * 3;
    coor4[p] = make_float4(src[0], src[1], src[2], 0.f);
  }
}

// ---------------- KNN: threshold-select, one query per 256-thread block -------
// Output = SET of 32 smallest keys (dist_bits<<32 | idx); order arbitrary
// (downstream max/mean/var are permutation-invariant over K).
// dist[0..15] in registers, dist[16..31] in LDS; NO recompute (crash-prone).
__global__ __launch_bounds__(256, 8) void kknn(const float4* __restrict__ coor4,
                                               const int* __restrict__ indx,
                                               int* __restrict__ knn) {
  __shared__ float sdist[16 * 256];           // 16KB: dist[it-16][tid]
  __shared__ float smin[128];                 // 4 waves x 32 smallest thread-mins
  __shared__ float smrg[64];                  // 2 pairwise-merged 32-lists
  __shared__ float sT;
  __shared__ unsigned long long cands[128];
  __shared__ unsigned long long ssort[128];
  __shared__ int ccnt;

  const int gid = blockIdx.x;
  const int b = gid >> 11, s = gid & 2047;
  const int tid = threadIdx.x;
  const int w = tid >> 6, lane = tid & 63;
  const float4* cb = coor4 + ((size_t)b << 13);
  const float4 q = cb[indx[s]];

  // pass 1a: dist 0..15 -> registers
  float rdist[16];
  float dmin = 3.4e38f;
#pragma unroll
  for (int it = 0; it < 16; ++it) {
    const float4 c = cb[tid + (it << 8)];
    const float dx = __fsub_rn(c.x, q.x);
    const float dy = __fsub_rn(c.y, q.y);
    const float dz = __fsub_rn(c.z, q.z);
    const float d =
        __fadd_rn(__fadd_rn(__fmul_rn(dx, dx), __fmul_rn(dy, dy)), __fmul_rn(dz, dz));
    rdist[it] = d;
    dmin = fminf(dmin, d);
  }
  // pass 1b: dist 16..31 -> LDS
#pragma unroll 8
  for (int it = 16; it < 32; ++it) {
    const float4 c = cb[tid + (it << 8)];
    const float dx = __fsub_rn(c.x, q.x);
    const float dy = __fsub_rn(c.y, q.y);
    const float dz = __fsub_rn(c.z, q.z);
    const float d =
        __fadd_rn(__fadd_rn(__fmul_rn(dx, dx), __fmul_rn(dy, dy)), __fmul_rn(dz, dz));
    sdist[(it - 16) * 256 + tid] = d;
    dmin = fminf(dmin, d);
  }
  if (tid == 0) ccnt = 0;
  if (tid < 128) cands[tid] = ~0ULL;

  // pass 2: T = exact 32nd smallest of the 256 thread-mins
  // (T >= d32: at most 31 elements lie strictly below d32, so at most 31
  //  thread-mins do; the 32nd-smallest min is >= d32.)
  float v = dmin;                             // per-wave bitonic sort (ascending)
#pragma unroll
  for (int k = 2; k <= 64; k <<= 1) {
#pragma unroll
    for (int j = k >> 1; j >= 1; j >>= 1) {
      const float o = __shfl_xor(v, j, 64);
      const bool dirAsc = ((lane & k) == 0);
      const bool lower = ((lane & j) == 0);
      const float lo = fminf(v, o), hi = fmaxf(v, o);
      v = (dirAsc == lower) ? lo : hi;
    }
  }
  if (lane < 32) smin[w * 32 + lane] = v;
  __syncthreads();
  if (w < 2) {                                // merge lists (2w, 2w+1) -> 32 smallest
    float a = (lane < 32) ? smin[w * 64 + lane] : smin[w * 64 + 32 + (63 - lane)];
#pragma unroll
    for (int j = 32; j >= 1; j >>= 1) {
      const float o = __shfl_xor(a, j, 64);
      const float lo = fminf(a, o), hi = fmaxf(a, o);
      a = ((lane & j) == 0) ? lo : hi;
    }
    if (lane < 32) smrg[w * 32 + lane] = a;
  }
  __syncthreads();
  if (w == 0) {                               // final merge -> 32nd smallest value
    float a = (lane < 32) ? smrg[lane] : smrg[32 + (63 - lane)];
#pragma unroll
    for (int j = 32; j >= 1; j >>= 1) {
      const float o = __shfl_xor(a, j, 64);
      const float lo = fminf(a, o), hi = fmaxf(a, o);
      a = ((lane & j) == 0) ? lo : hi;
    }
    if (lane == 31) sT = a;
  }
  __syncthreads();
  const float T = sT;

  // pass 3: compact candidates (dist <= T) from regs + LDS; E~34-40, cap 128
#pragma unroll
  for (int it = 0; it < 16; ++it) {
    const float d = rdist[it];
    if (d <= T) {
      const int pos = atomicAdd(&ccnt, 1);
      if (pos < 128)
        cands[pos] = ((unsigned long long)__float_as_uint(d) << 32) |
                     (unsigned int)(tid + (it << 8));
    }
  }
#pragma unroll 8
  for (int it = 16; it < 32; ++it) {
    const float d = sdist[(it - 16) * 256 + tid];
    if (d <= T) {
      const int pos = atomicAdd(&ccnt, 1);
      if (pos < 128)
        cands[pos] = ((unsigned long long)__float_as_uint(d) << 32) |
                     (unsigned int)(tid + (it << 8));
    }
  }
  __syncthreads();

  // pass 4: exact top-32 of <=128 candidates by u64 key
  if (w < 2) {                                // two parallel bitonic sort-64s
    unsigned long long kv = cands[w * 64 + lane];
#pragma unroll
    for (int k = 2; k <= 64; k <<= 1) {
#pragma unroll
      for (int j = k >> 1; j >= 1; j >>= 1) {
        const unsigned long long o = __shfl_xor(kv, j, 64);
        const bool dirAsc = ((lane & k) == 0);
        const bool lower = ((lane & j) == 0);
        const unsigned long long lo = o < kv ? o : kv;
        const unsigned long long hi = o < kv ? kv : o;
        kv = (dirAsc == lower) ? lo : hi;
      }
    }
    ssort[w * 64 + lane] = kv;
  }
  __syncthreads();
  if (w == 0) {                               // reverse-merge; lo-half holds 64 smallest
    const unsigned long long a = ssort[lane];
    const unsigned long long b2 = ssort[64 + 63 - lane];
    unsigned long long m = a < b2 ? a : b2;   // bitonic 64-seq
#pragma unroll
    for (int j = 32; j >= 1; j >>= 1) {
      const unsigned long long o = __shfl_xor(m, j, 64);
      const unsigned long long lo = o < m ? o : m;
      const unsigned long long hi = o < m ? m : o;
      m = ((lane & j) == 0) ? lo : hi;
    }
    if (lane < 32) knn[gid * 32 + lane] = (int)(unsigned int)m;
  }
}

// ---------------- phase kernels: MFMA fused GEMMs ----------------------------
// Wave w owns cols 32w..32w+31. Per lane: m = lane&31 (A row / D col), q2 = lane>>5.
// A layout: A[m=lane&31][k=q2*8+j]; B layout: B^T[n=lane&31][k=q2*8+j];
// C/D layout: col=lane&31, row=(reg&3)+8*(reg>>2)+4*q2  [m74/m101-verified].
// Layer-1 is K=128: A = [sx bf16 (k<64) | d bf16 (k>=64)], B = full w1.
// XCD map: batch = blockIdx&7 (one 2MB x-slice per XCD L2); depth-1 prefetch
// of indx/sx-row/knn-row for group g+1 overlaps group g's staging+MFMA.
template <int PHASE>
__global__ __launch_bounds__(256, 4) void kphase(
    const float* __restrict__ x, const int* __restrict__ indx,
    const int* __restrict__ knn, const float* __restrict__ b1,
    const unsigned short* __restrict__ w1b, const unsigned short* __restrict__ w2b,
    const float* __restrict__ b2, const float* __restrict__ st1,
    float* __restrict__ part, float* __restrict__ mout) {
  __shared__ __align__(16) float sx[64];
  __shared__ __align__(16) unsigned short sxb[72];   // bf16 sx (64 + pad)
  __shared__ __align__(16) unsigned short dls[32 * 68 + 8];
  __shared__ __align__(16) unsigned short h1[PHASE == 2 ? 32 * 136 : 8];

  const int tid = threadIdx.x;
  const int w = tid >> 6;
  const int lane = tid & 63;
  const int m = lane & 31, q2 = lane >> 5;
  const int col = (w << 5) + m;              // output channel of this lane
  const int r8 = tid >> 3, c8 = (tid & 7) * 8;  // staging map: row, col-base

  const int bb = blockIdx.x & 7;             // batch == target XCD
  const int jj = blockIdx.x >> 3;            // 0..255 chunk within batch
  const float* xb = x + (size_t)bb * (N_ * 64);
  const int gidbase = (bb << 11) + jj * GPB_;

  // group-invariant operands in registers
  bf8 bf1[8];
#pragma unroll
  for (int t = 0; t < 8; ++t)
    bf1[t] = *(const bf8*)&w1b[col * 128 + t * 16 + q2 * 8];
  bf8 bf2[8];
  float s1 = 0.f, t1 = 0.f, b2v = 0.f;
  if constexpr (PHASE == 2) {
#pragma unroll
    for (int t = 0; t < 8; ++t)
      bf2[t] = *(const bf8*)&w2b[col * 128 + t * 16 + q2 * 8];
    s1 = st1[col];
    t1 = st1[128 + col];
    b2v = b2[col];
  }
  (void)w2b; (void)b2; (void)st1; (void)mout;
  const float b1c = b1[col];

  float sum = 0.f, ssq = 0.f;

  // depth-1 prefetch for g = 0
  int idxp = indx[jj * GPB_];
  float sxv = (tid < 64) ? xb[(size_t)idxp * 64 + tid] : 0.f;
  int nbr = knn[(size_t)gidbase * 32 + r8];

#pragma unroll 1
  for (int g = 0; g < GPB_; ++g) {
    const int gid = gidbase + g;
    if (tid < 64) sx[tid] = sxv;
    __syncthreads();                         // A: sx visible; prior dls reads done

    // stage d = x[nbr] - sx as bf16 into dls (coalesced: 8 lanes per row)
    {
      const float* xrow = xb + (size_t)nbr * 64 + c8;
      const float4 xa = *(const float4*)(xrow);
      const float4 xc = *(const float4*)(xrow + 4);
      const float4 sa = *(const float4*)(sx + c8);
      const float4 sc = *(const float4*)(sx + c8 + 4);
      uint2 lo, hi;
      lo.x = bfpair(xa.x - sa.x, xa.y - sa.y);
      lo.y = bfpair(xa.z - sa.z, xa.w - sa.w);
      hi.x = bfpair(xc.x - sc.x, xc.y - sc.y);
      hi.y = bfpair(xc.z - sc.z, xc.w - sc.w);
      *(uint2*)&dls[r8 * 68 + c8] = lo;      // byte addr 136*r8+16k: 8B-aligned
      *(uint2*)&dls[r8 * 68 + c8 + 4] = hi;
    }
    if (tid < 16) {                          // pack sx -> bf16 (post-A)
      const float4 sv = *(const float4*)(sx + tid * 4);
      uint2 p;
      p.x = bfpair(sv.x, sv.y);
      p.y = bfpair(sv.z, sv.w);
      *(uint2*)&sxb[tid * 4] = p;
    }

    // prefetch g+1 chain (overlaps this group's MFMA; independent of LDS)
    if (g + 1 < GPB_) {
      const int s1n = jj * GPB_ + g + 1;
      const int idx1 = indx[s1n];
      sxv = (tid < 64) ? xb[(size_t)idx1 * 64 + tid] : 0.f;
      nbr = knn[(size_t)(gid + 1) * 32 + r8];
    }
    __syncthreads();                         // B: dls + sxb ready

    // A-frags: t<4 from sxb (k<64), t>=4 from dls (k>=64)
    bf8 af[8];
#pragma unroll
    for (int t = 0; t < 4; ++t) {
      union { bf8 v; uint2 u[2]; } fa;
      fa.u[0] = *(const uint2*)&sxb[t * 16 + q2 * 8];
      fa.u[1] = *(const uint2*)&sxb[t * 16 + q2 * 8 + 4];
      af[t] = fa.v;
    }
#pragma unroll
    for (int t = 0; t < 4; ++t) {
      union { bf8 v; uint2 u[2]; } fa;
      fa.u[0] = *(const uint2*)&dls[m * 68 + t * 16 + q2 * 8];
      fa.u[1] = *(const uint2*)&dls[m * 68 + t * 16 + q2 * 8 + 4];
      af[4 + t] = fa.v;
    }

    f32x16 acc;
#pragma unroll
    for (int r = 0; r < 16; ++r) acc[r] = b1c;
#pragma unroll
    for (int t = 0; t < 8; ++t)
      acc = __builtin_amdgcn_mfma_f32_32x32x16_bf16(af[t], bf1[t], acc, 0, 0, 0);

    if constexpr (PHASE == 1) {
#pragma unroll
      for (int r = 0; r < 16; ++r) {
        const float v = acc[r];
        sum += v;
        ssq = fmaf(v, v, ssq);
      }
    } else {
      // bn1 + relu -> h1 bf16 in LDS (C-layout scatter, row stride 136)
#pragma unroll
      for (int r = 0; r < 16; ++r) {
        const float hv = fmaxf(0.f, fmaf(acc[r], s1, t1));
        const int row = (r & 3) + ((r >> 2) << 3) + (q2 << 2);
        h1[row * 136 + col] = (unsigned short)bf1u(hv);
      }
      __syncthreads();                       // C: h1 ready

      f32x16 acc2;
#pragma unroll
      for (int r = 0; r < 16; ++r) acc2[r] = b2v;
#pragma unroll
      for (int t = 0; t < 8; ++t) {
        const bf8 a2 = *(const bf8*)&h1[m * 136 + t * 16 + q2 * 8];
        acc2 = __builtin_amdgcn_mfma_f32_32x32x16_bf16(a2, bf2[t], acc2, 0, 0, 0);
      }

      float mx = -1e30f;
#pragma unroll
      for (int r = 0; r < 16; ++r) {
        const float v = acc2[r];
        sum += v;
        ssq = fmaf(v, v, ssq);
        mx = fmaxf(mx, v);
      }
      mx = fmaxf(mx, __shfl_xor(mx, 32, 64));
      if (lane < 32) mout[(size_t)gid * 128 + col] = mx;
    }
  }

  // channel partials: each channel owned by exactly one wave
  sum += __shfl_xor(sum, 32, 64);
  ssq += __shfl_xor(ssq, 32, 64);
  if (lane < 32) {
    part[blockIdx.x * 256 + col] = sum;
    part[blockIdx.x * 256 + 128 + col] = ssq;
  }
}

// ---------------- stats reduce stage 1: 64 blocks, f64 partial sums ----------
__global__ __launch_bounds__(256) void kred1(const float* __restrict__ part,
                                             double* __restrict__ dbuf) {
  const int blk = blockIdx.x;                // 0..63: rows 32*blk..32*blk+31
  const int c = threadIdx.x;                 // 0..255 (128 sums | 128 ssqs)
  const float* p = part + (size_t)blk * 32 * 256 + c;
  double acc = 0.0;
#pragma unroll 8
  for (int r = 0; r < 32; ++r) acc += (double)p[r * 256];
  dbuf[blk * 256 + c] = acc;
}

// ---------------- stats reduce stage 2: finalize scale/shift -----------------
__global__ __launch_bounds__(256) void kred2(const double* __restrict__ dbuf,
                                             const float* __restrict__ gam,
                                             const float* __restrict__ bet,
                                             float* __restrict__ st) {
  __shared__ double sS[256];
  const int c = threadIdx.x;
  double acc = 0.0;
#pragma unroll 8
  for (int i = 0; i < 64; ++i) acc += dbuf[i * 256 + c];
  sS[c] = acc;
  __syncthreads();
  if (c < 128) {
    const double Sv = sS[c], SSv = sS[128 + c];
    const double cnt = 524288.0;             // B*S*K
    const double mean = Sv / cnt;
    const double var = SSv / cnt - mean * mean;
    const double scale = (double)gam[c] / sqrt(var + 1e-5);
    st[c] = (float)scale;
    st[128 + c] = (float)((double)bet[c] - mean * scale);
  }
}

// ---------------- final: out = relu(scale2 * max_k(y2) + shift2) -------------
__global__ __launch_bounds__(256) void kout(const float* __restrict__ m,
                                            const float* __restrict__ st2,
                                            float* __restrict__ out) {
  const int e4 = blockIdx.x * 256 + threadIdx.x;  // 524288 float4s
  const int o0 = (e4 & 31) * 4;
  const float4 v = ((const float4*)m)[e4];
  const float4 sc = *(const float4*)&st2[o0];
  const float4 sh = *(const float4*)&st2[128 + o0];
  float4 r;
  r.x = fmaxf(0.f, fmaf(v.x, sc.x, sh.x));
  r.y = fmaxf(0.f, fmaf(v.y, sc.y, sh.y));
  r.z = fmaxf(0.f, fmaf(v.z, sc.z, sh.z));
  r.w = fmaxf(0.f, fmaf(v.w, sc.w, sh.w));
  ((float4*)out)[e4] = r;
}

extern "C" void kernel_launch(void* const* d_in, const int* in_sizes, int n_in,
                              void* d_out, int out_size, void* d_ws, size_t ws_size,
                              hipStream_t stream) {
  (void)in_sizes; (void)n_in; (void)out_size; (void)ws_size;
  const float* x    = (const float*)d_in[0];
  const float* coor = (const float*)d_in[1];
  const int*   indx = (const int*)d_in[2];
  const float* w1   = (const float*)d_in[3];
  const float* b1   = (const float*)d_in[4];
  const float* g1   = (const float*)d_in[5];
  const float* be1  = (const float*)d_in[6];
  const float* w2   = (const float*)d_in[7];
  const float* b2   = (const float*)d_in[8];
  const float* g2   = (const float*)d_in[9];
  const float* be2  = (const float*)d_in[10];
  float* out = (float*)d_out;

  char* ws = (char*)d_ws;
  int*            knn   = (int*)(ws + 0);
  float*          mbuf  = (float*)(ws + 2097152);
  float*          part1 = (float*)(ws + 10485760);
  float4*         coor4 = (float4*)(ws + 10485760); // aliases part1 (disjoint lifetime)
  float*          part2 = (float*)(ws + 12582912);
  unsigned short* w1b   = (unsigned short*)(ws + 14680064);
  unsigned short* w2b   = (unsigned short*)(ws + 14712832);
  float*          st1   = (float*)(ws + 14745600);
  float*          st2   = (float*)(ws + 14746624);
  double*         dbuf  = (double*)(ws + 14747648);

  float* outc = out + 2097152;   // sampled_coor region of d_out

  kprep<<<576, 256, 0, stream>>>(w1, w2, coor, indx, w1b, w2b, outc, coor4);
  kknn<<<16384, 256, 0, stream>>>(coor4, indx, knn);
  kphase<1><<<2048, 256, 0, stream>>>(x, indx, knn, b1, w1b, w2b, b2, nullptr,
                                      part1, nullptr);
  kred1<<<64, 256, 0, stream>>>(part1, dbuf);
  kred2<<<1, 256, 0, stream>>>(dbuf, g1, be1, st1);
  kphase<2><<<2048, 256, 0, stream>>>(x, indx, knn, b1, w1b, w2b, b2, st1,
                                      part2, mbuf);
  kred1<<<64, 256, 0, stream>>>(part2, dbuf);
  kred2<<<1, 256, 0, stream>>>(dbuf, g2, be2, st2);
  kout<<<2048, 256, 0, stream>>>(mbuf, st2, out);
}